// Round 7
// baseline (891.135 us; speedup 1.0000x reference)
//
#include <hip/hip_runtime.h>
#include <cstdint>
#include <cstddef>

#define GRID_DIM 160
#define GRID_VOX (GRID_DIM * GRID_DIM * GRID_DIM)
#define CIN 64
#define COUT 96
#define NK 27
#define NSIDE 26
#define CAP_SIDE 65536          // capacity per side-offset pair list (measured ~16k)
#define PAIRS_PER_BLOCK 64
#define CURS_STRIDE 16          // cursors 64B apart -> no same-line atomic contention

// ---------------------------------------------------------------------------
// K1: scatter point indices into dense voxel grid. Grid pre-memset to -1.
// atomicMax = last-update-wins (matches numpy scatter order), verified R1.
// ---------------------------------------------------------------------------
__global__ __launch_bounds__(256) void scatter_kernel(
    const int* __restrict__ coords, int* __restrict__ grid, int N)
{
    int i = blockIdx.x * 256 + threadIdx.x;
    if (i >= N) return;
    int lin = (coords[i * 3] * GRID_DIM + coords[i * 3 + 1]) * GRID_DIM
            + coords[i * 3 + 2];
    atomicMax(&grid[lin], i);
}

// ---------------------------------------------------------------------------
// K2: repack weight [27][64][96] -> [27][16][96][4] (wt2[k][ci4][c][j]).
// ---------------------------------------------------------------------------
__global__ __launch_bounds__(256) void repack_w(
    const float* __restrict__ w, float* __restrict__ wt2)
{
    int idx = blockIdx.x * 256 + threadIdx.x;
    if (idx >= NK * CIN * COUT) return;
    int k   = idx / (CIN * COUT);
    int r   = idx - k * (CIN * COUT);
    int ci  = r / COUT;
    int c   = r - ci * COUT;
    wt2[(((size_t)k * 16 + (ci >> 2)) * COUT + c) * 4 + (ci & 3)] = w[idx];
}

// ---------------------------------------------------------------------------
// K3: build rulebook with mirror symmetry + forced probe MLP (unchanged R4).
// ---------------------------------------------------------------------------
__global__ __launch_bounds__(256, 4) void fill_pairs(
    const int* __restrict__ coords, const int* __restrict__ grid,
    int* __restrict__ cursors, int2* __restrict__ pairs,
    int* __restrict__ winner, int N)
{
    int p = blockIdx.x * 256 + threadIdx.x;
    if (p >= N) return;
    int lane = threadIdx.x & 63;

    int c0 = coords[p * 3], c1 = coords[p * 3 + 1], c2 = coords[p * 3 + 2];
    int ownLin = (c0 * GRID_DIM + c1) * GRID_DIM + c2;

    int nidx[13];
    #pragma unroll
    for (int k = 0; k < 13; ++k) {
        int dz = k / 9 - 1, dy = (k / 3) % 3 - 1, dx = k % 3 - 1;
        int a0 = c0 + dz, a1 = c1 + dy, a2 = c2 + dx;
        bool v = ((unsigned)a0 < GRID_DIM) & ((unsigned)a1 < GRID_DIM) &
                 ((unsigned)a2 < GRID_DIM);
        int lin = v ? (a0 * GRID_DIM + a1) * GRID_DIM + a2 : ownLin;
        int g = grid[lin];
        nidx[k] = v ? g : -1;
    }
    int w = grid[ownLin];

    int chk = w;
    #pragma unroll
    for (int k = 0; k < 13; ++k) chk += nidx[k];
    asm volatile("" :: "v"(chk));

    winner[p] = w;
    bool isW = (w == p);

    #pragma unroll
    for (int k = 0; k < 13; ++k) {
        int q = nidx[k];
        bool valid = q >= 0;

        unsigned long long m1 = __ballot(valid);
        if (m1) {
            int leader = __ffsll((long long)m1) - 1;
            int cnt    = __popcll(m1);
            int off    = __popcll(m1 & ((1ull << lane) - 1ull));
            int base = 0;
            if (lane == leader) base = atomicAdd(&cursors[k * CURS_STRIDE], cnt);
            base = __shfl(base, leader);
            int slot = base + off;
            if (valid && slot < CAP_SIDE)
                pairs[(size_t)k * CAP_SIDE + slot] = make_int2(q, p);
        }

        bool mv = valid && isW;
        unsigned long long m2 = __ballot(mv);
        if (m2) {
            int leader = __ffsll((long long)m2) - 1;
            int cnt    = __popcll(m2);
            int off    = __popcll(m2 & ((1ull << lane) - 1ull));
            int base = 0;
            if (lane == leader) base = atomicAdd(&cursors[(25 - k) * CURS_STRIDE], cnt);
            base = __shfl(base, leader);
            int slot = base + off;
            if (mv && slot < CAP_SIDE)
                pairs[(size_t)(25 - k) * CAP_SIDE + slot] = make_int2(w, q);
        }
    }
}

// ---------------------------------------------------------------------------
// K4: side-offset gather-GEMM-scatter, 4-pair register tile per half-wave.
// Per ci4: 3 LDS float4 reads shared across 4 feature rows -> LDS traffic /4
// (was LDS-BW-bound at 24.6KB/pair; model: 428k cy/CU -> ~110k).
// ---------------------------------------------------------------------------
__global__ __launch_bounds__(256) void conv_side(
    const float* __restrict__ feat, const float* __restrict__ wt2,
    const int* __restrict__ cursors, const int2* __restrict__ pairs,
    float* __restrict__ out)
{
    int si = blockIdx.y;                    // 0..25
    int k  = (si < 13) ? si : si + 1;       // weight index (skip center 13)
    int cnt = cursors[si * CURS_STRIDE];
    if (cnt > CAP_SIDE) cnt = CAP_SIDE;
    int base = blockIdx.x * PAIRS_PER_BLOCK;
    if (base >= cnt) return;                // uniform early-exit (before barrier)

    __shared__ float4 wlds[16 * COUT];      // 24576 B
    {
        const float4* src = (const float4*)(wt2 + (size_t)k * 16 * COUT * 4);
        for (int i = threadIdx.x; i < 16 * COUT; i += 256) wlds[i] = src[i];
    }
    __syncthreads();

    int hw = threadIdx.x >> 5;              // half-wave 0..7
    int h  = threadIdx.x & 31;
    const int2* seg = pairs + (size_t)si * CAP_SIDE;

    #pragma unroll
    for (int g = 0; g < 2; ++g) {           // 2 groups of 32 pairs per block
        int idx0 = base + g * 32 + hw * 4;  // this half-wave's 4 pairs
        if (idx0 >= cnt) continue;          // half-wave-uniform
        int nv = cnt - idx0; if (nv > 4) nv = 4;

        int2 pr[4];
        #pragma unroll
        for (int i = 0; i < 4; ++i)
            pr[i] = seg[(i < nv) ? idx0 + i : idx0];   // pad re-reads idx0

        const float4* fp[4];
        #pragma unroll
        for (int i = 0; i < 4; ++i)
            fp[i] = (const float4*)(feat + (size_t)pr[i].x * CIN);

        float a0[4] = {0,0,0,0}, a1[4] = {0,0,0,0}, a2[4] = {0,0,0,0};

        #pragma unroll
        for (int ci4 = 0; ci4 < 16; ++ci4) {
            const float4* wv = &wlds[ci4 * COUT];
            float4 wa = wv[h], wb = wv[h + 32], wc = wv[h + 64];
            #pragma unroll
            for (int i = 0; i < 4; ++i) {
                float4 f = fp[i][ci4];
                a0[i] = fmaf(f.w, wa.w, fmaf(f.z, wa.z, fmaf(f.y, wa.y, fmaf(f.x, wa.x, a0[i]))));
                a1[i] = fmaf(f.w, wb.w, fmaf(f.z, wb.z, fmaf(f.y, wb.y, fmaf(f.x, wb.x, a1[i]))));
                a2[i] = fmaf(f.w, wc.w, fmaf(f.z, wc.z, fmaf(f.y, wc.y, fmaf(f.x, wc.x, a2[i]))));
            }
        }

        #pragma unroll
        for (int i = 0; i < 4; ++i) {
            if (i < nv) {
                float* op = out + (size_t)pr[i].y * COUT;
                atomicAdd(op + h,      a0[i]);
                atomicAdd(op + h + 32, a1[i]);
                atomicAdd(op + h + 64, a2[i]);
            }
        }
    }
}

// ---------------------------------------------------------------------------
// K5: center + bias + LayerNorm + ReLU, 4-point register tile per half-wave
// (same LDS-amortization as K4). Winners only; losers fixed by dup_fix.
// ---------------------------------------------------------------------------
__global__ __launch_bounds__(256) void center_ln_relu(
    const float* __restrict__ feat, const int* __restrict__ winner,
    const float* __restrict__ wt2,
    const float* __restrict__ bias, const float* __restrict__ gamma,
    const float* __restrict__ beta, float* __restrict__ out, int N)
{
    __shared__ float4 wlds[16 * COUT];
    {
        const float4* src = (const float4*)(wt2 + (size_t)13 * 16 * COUT * 4);
        for (int i = threadIdx.x; i < 16 * COUT; i += 256) wlds[i] = src[i];
    }
    __syncthreads();

    int hw = threadIdx.x >> 5;
    int h  = threadIdx.x & 31;
    float b0 = bias[h], b1 = bias[h + 32], b2 = bias[h + 64];
    float g0 = gamma[h], g1 = gamma[h + 32], g2 = gamma[h + 64];
    float e0 = beta[h],  e1 = beta[h + 32],  e2 = beta[h + 64];

    int pb = blockIdx.x * 128 + hw * 16;    // 16 points per half-wave

    #pragma unroll
    for (int j = 0; j < 4; ++j) {           // 4 tiles of 4 points
        int p0 = pb + j * 4;
        if (p0 >= N) break;

        int wn[4];
        const float4* fp[4];
        float* op[4];
        #pragma unroll
        for (int i = 0; i < 4; ++i) {
            int p = p0 + i;
            wn[i] = (p < N) ? winner[p] : -1;
            fp[i] = (const float4*)(feat + (size_t)min(p, N - 1) * CIN);
            op[i] = out + (size_t)min(p, N - 1) * COUT;
        }

        float a0[4], a1[4], a2[4];
        #pragma unroll
        for (int i = 0; i < 4; ++i) {
            a0[i] = op[i][h]      + b0;
            a1[i] = op[i][h + 32] + b1;
            a2[i] = op[i][h + 64] + b2;
        }

        #pragma unroll
        for (int ci4 = 0; ci4 < 16; ++ci4) {
            const float4* wv = &wlds[ci4 * COUT];
            float4 wa = wv[h], wb = wv[h + 32], wc = wv[h + 64];
            #pragma unroll
            for (int i = 0; i < 4; ++i) {
                float4 f = fp[i][ci4];
                a0[i] = fmaf(f.w, wa.w, fmaf(f.z, wa.z, fmaf(f.y, wa.y, fmaf(f.x, wa.x, a0[i]))));
                a1[i] = fmaf(f.w, wb.w, fmaf(f.z, wb.z, fmaf(f.y, wb.y, fmaf(f.x, wb.x, a1[i]))));
                a2[i] = fmaf(f.w, wc.w, fmaf(f.z, wc.z, fmaf(f.y, wc.y, fmaf(f.x, wc.x, a2[i]))));
            }
        }

        #pragma unroll
        for (int i = 0; i < 4; ++i) {
            float s  = a0[i] + a1[i] + a2[i];
            float s2 = a0[i] * a0[i] + a1[i] * a1[i] + a2[i] * a2[i];
            #pragma unroll
            for (int off = 16; off >= 1; off >>= 1) {
                s  += __shfl_xor(s, off);   // stays within the 32-lane half
                s2 += __shfl_xor(s2, off);
            }
            float mu  = s * (1.0f / COUT);
            float var = s2 * (1.0f / COUT) - mu * mu;
            float rs  = rsqrtf(var + 1e-5f);

            float o0 = (a0[i] - mu) * rs * g0 + e0;
            float o1 = (a1[i] - mu) * rs * g1 + e1;
            float o2 = (a2[i] - mu) * rs * g2 + e2;
            int p = p0 + i;
            if (p < N && wn[i] == p) {      // winners only
                op[i][h]      = o0 > 0.f ? o0 : 0.f;
                op[i][h + 32] = o1 > 0.f ? o1 : 0.f;
                op[i][h + 64] = o2 > 0.f ? o2 : 0.f;
            }
        }
    }
}

// ---------------------------------------------------------------------------
// K6: duplicate-coordinate fixup — losers copy the winner's final row.
// ---------------------------------------------------------------------------
__global__ __launch_bounds__(256) void dup_fix(
    const int* __restrict__ winner, float* __restrict__ out, int N)
{
    int p = blockIdx.x * 8 + (threadIdx.x >> 5);
    if (p >= N) return;
    int w = winner[p];
    if (w == p) return;
    int h = threadIdx.x & 31;
    out[(size_t)p * COUT + h]      = out[(size_t)w * COUT + h];
    out[(size_t)p * COUT + h + 32] = out[(size_t)w * COUT + h + 32];
    out[(size_t)p * COUT + h + 64] = out[(size_t)w * COUT + h + 64];
}

// ---------------------------------------------------------------------------
extern "C" void kernel_launch(void* const* d_in, const int* in_sizes, int n_in,
                              void* d_out, int out_size, void* d_ws, size_t ws_size,
                              hipStream_t stream)
{
    const float* feat   = (const float*)d_in[0];
    const int*   coords = (const int*)d_in[1];
    const float* weight = (const float*)d_in[2];
    const float* bias   = (const float*)d_in[3];
    const float* gamma  = (const float*)d_in[4];
    const float* beta   = (const float*)d_in[5];
    float* out = (float*)d_out;

    int N = in_sizes[0] / CIN;   // 262144

    char* wsp = (char*)d_ws;
    int*   grid_ws = (int*)wsp;                       wsp += (size_t)GRID_VOX * 4;
    float* wt2     = (float*)wsp;                     wsp += (size_t)NK * CIN * COUT * 4;
    int*   cursors = (int*)wsp;                       wsp += (size_t)NSIDE * CURS_STRIDE * 4;
    int*   winner  = (int*)wsp;                       wsp += (size_t)N * 4;
    int2*  pairs   = (int2*)wsp;

    hipMemsetAsync(grid_ws, 0xFF, (size_t)GRID_VOX * 4, stream);
    hipMemsetAsync(cursors, 0, (size_t)NSIDE * CURS_STRIDE * 4, stream);
    hipMemsetAsync(out, 0, (size_t)N * COUT * 4, stream);

    scatter_kernel<<<(N + 255) / 256, 256, 0, stream>>>(coords, grid_ws, N);
    repack_w<<<(NK * CIN * COUT + 255) / 256, 256, 0, stream>>>(weight, wt2);
    fill_pairs<<<(N + 255) / 256, 256, 0, stream>>>(coords, grid_ws, cursors,
                                                    pairs, winner, N);

    dim3 gside(CAP_SIDE / PAIRS_PER_BLOCK, 26);       // early-exit tail
    conv_side<<<gside, 256, 0, stream>>>(feat, wt2, cursors, pairs, out);

    center_ln_relu<<<(N + 127) / 128, 256, 0, stream>>>(
        feat, winner, wt2, bias, gamma, beta, out, N);

    dup_fix<<<(N + 7) / 8, 256, 0, stream>>>(winner, out, N);
}